// Round 10
// baseline (572.384 us; speedup 1.0000x reference)
//
#include <hip/hip_runtime.h>
#include <math.h>

// B=32, C=3, H=W=512, window 11, sigma 1.5, VALID conv -> 502x502
#define H 512
#define W 512
#define OUT_H 502
#define OUT_W 502
#define C1c 1.0e-4f   // (0.01*1)^2
#define C2c 9.0e-4f   // (0.03*1)^2

#define TH 144            // output rows per block
#define NR 154            // TH+10 input rows = 7*22 (pair- and phase-aligned)
#define HALO 10
#define SPAN 64           // output cols per WAVE (wave-private strip)
#define SLOTQ 80          // float4 entries per row-slot per wave (74 used)

// Row-streaming SSIM, wave-private staging, barrier-free, PAIR-ROW pipeline.
// R10 vs R9: the 11 pair-phases are explicit template instantiations
// pair_step<0..10>() instead of a #pragma-unroll loop. R9's WRITE_SIZE
// (84.8 MB/dispatch scratch) + VGPR=64 is the signature of the unroller
// dropping the pragma on the ~300-instr body: phase p became RUNTIME ->
// g[(p-a)%11] / a0[pp] runtime-indexed -> arrays demoted to scratch
// (rule: runtime-indexed arrays never stay in registers). Template
// parameters make every phase index compile-time by construction.
//  - wave-private strips: DS ops in-order within a wave -> no s_barrier, no
//    per-row vmcnt/lgkmcnt drain; wave_barrier only pins compiler order.
//  - pairing: two independent h-pass chains per step (row r+1's ds_reads
//    issue under row r's FMAs); per-row loop/branch/addr overhead halved.
//  - float4 staging (x1,x2,x1*x2,x1^2), x2^2 per tap (R5/R6 A/B verdict).
//  - 55 phase accumulators, first-write-mul; weights in SGPR.
__global__ __launch_bounds__(256, 4)
void ssim_kernel(const float* __restrict__ img1,
                 const float* __restrict__ img2,
                 float* __restrict__ out);

template<int I>
__device__ __forceinline__ void pair_step(
    int rb, int& ro, int rocap,
    const float* __restrict__ q1, const float* __restrict__ q2,
    const float* __restrict__ qh1, const float* __restrict__ qh2,
    bool hl, float cmask, int Y0, int oyb,
    float4* stA, float4* stB, int lane,
    const float (&g)[11],
    float& a1, float& a2, float& b1, float& b2,
    float& ha1, float& ha2, float& hb1, float& hb2,
    float (&A0)[11], float (&A1)[11], float (&A2)[11],
    float (&A3)[11], float (&A4)[11],
    float& lsum)
{
    constexpr int p  = (2 * I) % 11;        // phase of row r — compile-time
    constexpr int pp = (p + 1) % 11;        // phase of row r+1
    constexpr int e2 = (p + 2) % 11;        // second flush slot
    const int r = rb + 2 * I;

    // stage the pair: float4(x1, x2, x1*x2, x1^2)
    stA[lane] = make_float4(a1, a2, a1 * a2, a1 * a1);
    stB[lane] = make_float4(b1, b2, b1 * b2, b1 * b1);
    if (hl) {
        stA[SPAN + lane] = make_float4(ha1, ha2, ha1 * ha2, ha1 * ha1);
        stB[SPAN + lane] = make_float4(hb1, hb2, hb1 * hb2, hb1 * hb1);
    }

    // prefetch next pair (ro wave-uniform: SALU add+min)
    ro = min(ro + 2 * W, rocap);
    a1 = q1[ro];     a2 = q2[ro];
    b1 = q1[ro + W]; b2 = q2[ro + W];
    if (hl) { ha1 = qh1[ro]; ha2 = qh2[ro]; hb1 = qh1[ro + W]; hb2 = qh2[ro + W]; }

    __builtin_amdgcn_wave_barrier();   // pin: writes above, reads below

    // two independent horizontal 11-tap chains
    float hA0, hA1, hA2, hA3, hA4;
    float hB0, hB1, hB2, hB3, hB4;
    {
        const float4* ra  = stA + lane;
        const float4* rb2 = stB + lane;
#pragma unroll
        for (int t = 0; t < 11; ++t) {
            const float4 v = ra[t];          // ds_read_b128
            const float w = g[t];
            const float q22 = v.y * v.y;
            if (t == 0) {
                hA0 = w * v.x; hA1 = w * v.y; hA2 = w * v.w;
                hA3 = w * q22; hA4 = w * v.z;
            } else {
                hA0 = fmaf(w, v.x, hA0); hA1 = fmaf(w, v.y, hA1);
                hA2 = fmaf(w, v.w, hA2); hA3 = fmaf(w, q22, hA3);
                hA4 = fmaf(w, v.z, hA4);
            }
        }
#pragma unroll
        for (int t = 0; t < 11; ++t) {
            const float4 v = rb2[t];         // ds_read_b128
            const float w = g[t];
            const float q22 = v.y * v.y;
            if (t == 0) {
                hB0 = w * v.x; hB1 = w * v.y; hB2 = w * v.w;
                hB3 = w * q22; hB4 = w * v.z;
            } else {
                hB0 = fmaf(w, v.x, hB0); hB1 = fmaf(w, v.y, hB1);
                hB2 = fmaf(w, v.w, hB2); hB3 = fmaf(w, q22, hB3);
                hB4 = fmaf(w, v.z, hB4);
            }
        }
    }

    __builtin_amdgcn_wave_barrier();   // pin: reads above next pair's writes

    // scatter row r (phase p): slot a==p gets mul (flushed last pair)
#pragma unroll
    for (int a = 0; a < 11; ++a) {
        const float w = g[(p - a + 11) % 11];   // compile-time index
        if (a == p) {
            A0[a] = w * hA0; A1[a] = w * hA1; A2[a] = w * hA2;
            A3[a] = w * hA3; A4[a] = w * hA4;
        } else {
            A0[a] = fmaf(w, hA0, A0[a]); A1[a] = fmaf(w, hA1, A1[a]);
            A2[a] = fmaf(w, hA2, A2[a]); A3[a] = fmaf(w, hA3, A3[a]);
            A4[a] = fmaf(w, hA4, A4[a]);
        }
    }

    // flush slot pp: output row oy = Y0 + r - 10
    if (r >= 10) {
        const int oy = Y0 + r - 10;
        if (oy >= oyb) {
            const float m1 = A0[pp], m2 = A1[pp];
            const float m1s = m1 * m1, m2s = m2 * m2, m12 = m1 * m2;
            const float sig1  = A2[pp] - m1s;
            const float sig2  = A3[pp] - m2s;
            const float sig12 = A4[pp] - m12;
            const float num = (2.f * m12 + C1c) * (2.f * sig12 + C2c);
            const float den = (m1s + m2s + C1c) * (sig1 + sig2 + C2c);
            lsum = fmaf(cmask, num * __builtin_amdgcn_rcpf(den), lsum);
        }
    }

    // scatter row r+1 (phase pp): slot a==pp gets mul (just flushed)
#pragma unroll
    for (int a = 0; a < 11; ++a) {
        const float w = g[(pp - a + 11) % 11];
        if (a == pp) {
            A0[a] = w * hB0; A1[a] = w * hB1; A2[a] = w * hB2;
            A3[a] = w * hB3; A4[a] = w * hB4;
        } else {
            A0[a] = fmaf(w, hB0, A0[a]); A1[a] = fmaf(w, hB1, A1[a]);
            A2[a] = fmaf(w, hB2, A2[a]); A3[a] = fmaf(w, hB3, A3[a]);
            A4[a] = fmaf(w, hB4, A4[a]);
        }
    }

    // flush slot e2: output row oy2 = Y0 + r - 9
    if (r >= 10) {
        const int oy2 = Y0 + r - 9;
        if (oy2 >= oyb) {
            const float m1 = A0[e2], m2 = A1[e2];
            const float m1s = m1 * m1, m2s = m2 * m2, m12 = m1 * m2;
            const float sig1  = A2[e2] - m1s;
            const float sig2  = A3[e2] - m2s;
            const float sig12 = A4[e2] - m12;
            const float num = (2.f * m12 + C1c) * (2.f * sig12 + C2c);
            const float den = (m1s + m2s + C1c) * (sig1 + sig2 + C2c);
            lsum = fmaf(cmask, num * __builtin_amdgcn_rcpf(den), lsum);
        }
    }
}

__global__ __launch_bounds__(256, 4)
void ssim_kernel(const float* __restrict__ img1,
                 const float* __restrict__ img2,
                 float* __restrict__ out) {
    __shared__ float4 stg[4][2][SLOTQ];   // [wave][rowslot][col], 10240 B
    __shared__ float wsum[4];

    const int tid  = threadIdx.x;
    const int wid  = tid >> 6;
    const int lane = tid & 63;

    // Gaussian weights (runtime expf to match reference), pinned to SGPR
    float g[11];
    {
        float s = 0.f;
#pragma unroll
        for (int i = 0; i < 11; ++i) {
            float d = (float)(i - 5);
            g[i] = expf(-d * d * (1.0f / 4.5f));
            s += g[i];
        }
        float inv = 1.0f / s;
#pragma unroll
        for (int i = 0; i < 11; ++i) {
            g[i] *= inv;
            g[i] = __uint_as_float(__builtin_amdgcn_readfirstlane(__float_as_uint(g[i])));
        }
    }

    const int base = blockIdx.x * 256 + wid * SPAN;  // strip origin
    const int oyb  = blockIdx.y * TH;                // output rows owned
    const int Y0   = min(oyb, H - NR);               // shift last tile up
    const int plane = blockIdx.z;                    // b*3 + c
    const size_t pbase = (size_t)plane * (H * W);
    const float* __restrict__ p1 = img1 + pbase;
    const float* __restrict__ p2 = img2 + pbase;

    const int gx = base + lane;                      // main column (<512)
    const int hx = min(base + SPAN + lane, W - 1);   // halo column (lanes<10)
    const float cmask = (gx < OUT_W) ? 1.0f : 0.0f;  // discard cols 502..511
    const bool hl = (lane < HALO);

    const float* __restrict__ q1  = p1 + gx;
    const float* __restrict__ q2  = p2 + gx;
    const float* __restrict__ qh1 = p1 + hx;
    const float* __restrict__ qh2 = p2 + hx;

    float4* const stA = stg[wid][0];
    float4* const stB = stg[wid][1];

    // 11 phase slots of vertical partial sums, 5 quantities
    float A0[11], A1[11], A2[11], A3[11], A4[11];
#pragma unroll
    for (int i = 0; i < 11; ++i) { A0[i]=0.f; A1[i]=0.f; A2[i]=0.f; A3[i]=0.f; A4[i]=0.f; }

    float lsum = 0.f;

    int ro = Y0 * W;
    const int rocap = (H - 2) * W;   // ro+W stays in-bounds after clamp

    // prime prefetch (rows Y0, Y0+1)
    float a1 = q1[ro],     a2 = q2[ro];
    float b1 = q1[ro + W], b2 = q2[ro + W];
    float ha1 = 0.f, ha2 = 0.f, hb1 = 0.f, hb2 = 0.f;
    if (hl) { ha1 = qh1[ro]; ha2 = qh2[ro]; hb1 = qh1[ro + W]; hb2 = qh2[ro + W]; }

#pragma unroll 1
    for (int rb = 0; rb < NR; rb += 22) {
        // 11 pair-phases, phases compile-time via template parameter
        pair_step<0>(rb, ro, rocap, q1, q2, qh1, qh2, hl, cmask, Y0, oyb,
                     stA, stB, lane, g, a1, a2, b1, b2, ha1, ha2, hb1, hb2,
                     A0, A1, A2, A3, A4, lsum);
        pair_step<1>(rb, ro, rocap, q1, q2, qh1, qh2, hl, cmask, Y0, oyb,
                     stA, stB, lane, g, a1, a2, b1, b2, ha1, ha2, hb1, hb2,
                     A0, A1, A2, A3, A4, lsum);
        pair_step<2>(rb, ro, rocap, q1, q2, qh1, qh2, hl, cmask, Y0, oyb,
                     stA, stB, lane, g, a1, a2, b1, b2, ha1, ha2, hb1, hb2,
                     A0, A1, A2, A3, A4, lsum);
        pair_step<3>(rb, ro, rocap, q1, q2, qh1, qh2, hl, cmask, Y0, oyb,
                     stA, stB, lane, g, a1, a2, b1, b2, ha1, ha2, hb1, hb2,
                     A0, A1, A2, A3, A4, lsum);
        pair_step<4>(rb, ro, rocap, q1, q2, qh1, qh2, hl, cmask, Y0, oyb,
                     stA, stB, lane, g, a1, a2, b1, b2, ha1, ha2, hb1, hb2,
                     A0, A1, A2, A3, A4, lsum);
        pair_step<5>(rb, ro, rocap, q1, q2, qh1, qh2, hl, cmask, Y0, oyb,
                     stA, stB, lane, g, a1, a2, b1, b2, ha1, ha2, hb1, hb2,
                     A0, A1, A2, A3, A4, lsum);
        pair_step<6>(rb, ro, rocap, q1, q2, qh1, qh2, hl, cmask, Y0, oyb,
                     stA, stB, lane, g, a1, a2, b1, b2, ha1, ha2, hb1, hb2,
                     A0, A1, A2, A3, A4, lsum);
        pair_step<7>(rb, ro, rocap, q1, q2, qh1, qh2, hl, cmask, Y0, oyb,
                     stA, stB, lane, g, a1, a2, b1, b2, ha1, ha2, hb1, hb2,
                     A0, A1, A2, A3, A4, lsum);
        pair_step<8>(rb, ro, rocap, q1, q2, qh1, qh2, hl, cmask, Y0, oyb,
                     stA, stB, lane, g, a1, a2, b1, b2, ha1, ha2, hb1, hb2,
                     A0, A1, A2, A3, A4, lsum);
        pair_step<9>(rb, ro, rocap, q1, q2, qh1, qh2, hl, cmask, Y0, oyb,
                     stA, stB, lane, g, a1, a2, b1, b2, ha1, ha2, hb1, hb2,
                     A0, A1, A2, A3, A4, lsum);
        pair_step<10>(rb, ro, rocap, q1, q2, qh1, qh2, hl, cmask, Y0, oyb,
                      stA, stB, lane, g, a1, a2, b1, b2, ha1, ha2, hb1, hb2,
                      A0, A1, A2, A3, A4, lsum);
    }

    // per-wave reduce, then one cross-wave combine + one atomic per block
#pragma unroll
    for (int off = 32; off > 0; off >>= 1) lsum += __shfl_down(lsum, off, 64);
    if (lane == 0) wsum[wid] = lsum;
    __syncthreads();
    if (tid == 0) {
        const float inv_count = 1.0f / (3.0f * (float)OUT_H * (float)OUT_W);
        const float total = (wsum[0] + wsum[1] + wsum[2] + wsum[3]) * inv_count;
        atomicAdd(&out[plane / 3], total);
    }
}

__global__ void zero_out(float* out, int n) {
    int i = threadIdx.x + blockIdx.x * blockDim.x;
    if (i < n) out[i] = 0.f;
}

extern "C" void kernel_launch(void* const* d_in, const int* in_sizes, int n_in,
                              void* d_out, int out_size, void* d_ws, size_t ws_size,
                              hipStream_t stream) {
    const float* img1 = (const float*)d_in[0];
    const float* img2 = (const float*)d_in[1];
    float* out = (float*)d_out;

    zero_out<<<1, 64, 0, stream>>>(out, out_size);

    const int nplanes = in_sizes[0] / (H * W);          // 96
    dim3 grid(W / 256,                                  // 2 col-tiles (4 strips each)
              (OUT_H + TH - 1) / TH,                    // 4 row-tiles
              nplanes);                                 // 96 planes -> 768 blocks
    ssim_kernel<<<grid, 256, 0, stream>>>(img1, img2, out);
}

// Round 11
// 268.286 us; speedup vs baseline: 2.1335x; 2.1335x over previous
//
#include <hip/hip_runtime.h>
#include <math.h>

// B=32, C=3, H=W=512, window 11, sigma 1.5, VALID conv -> 502x502
#define H 512
#define W 512
#define OUT_H 502
#define OUT_W 502
#define C1c 1.0e-4f   // (0.01*1)^2
#define C2c 9.0e-4f   // (0.03*1)^2

#define TH 56             // output rows per block (594 staged rows total: minimum)
#define NR 66             // TH+10 input rows, 6*11 (phase-aligned)
#define WSPAN 128         // output cols per WAVE (2 per lane)
#define SLOTQ 72          // 69 float4 units staged (+pad), per wave

// Row-streaming SSIM: R1's 2-col-per-lane payload on R5's wave-private,
// barrier-free chassis. Work-normalized history: R1 (2col+barrier) 111,
// R0 (1col+barrier) 114.5, R5 (1col+no-barrier) 131 -> combine R1's LDS
// diet (3 b128/col vs 11; products once per element serving 2 cols) with
// R5's barrier elimination (no per-row vmcnt/lgkmcnt drain; -24us proven).
//  - wave w owns cols [128w,128w+128); lane l computes (2l,2l+1) from staged
//    units l..l+5; lanes 0..4 stage the 10-col halo (units 64..68) from
//    global (clamped for wave 3; garbage feeds only cmask-discarded cols).
//  - wave-private strip: DS ops in-order within a wave -> no __syncthreads;
//    wave_barrier() only pins compiler order. Single-slot buffer (no ring).
//  - 110 phase accumulators (55 x 2 cols), first-write-mul (no zeroing);
//    weights pinned to SGPR. Plain #pragma unroll 11-phase loop, per-row
//    body ~R1-size (R1-proven clean codegen; NO templates, NO pair body —
//    R8/R9/R10 all scratch-cursed at 2x body size).
//  - launch_bounds(256,2): R1-verified cap; R3 proved tight caps spill.
__global__ __launch_bounds__(256, 2)
void ssim_kernel(const float* __restrict__ img1,
                 const float* __restrict__ img2,
                 float* __restrict__ out) {
    __shared__ float4 stg[4][SLOTQ];   // per-wave strips, 4608 B
    __shared__ float wsum[4];

    const int tid  = threadIdx.x;
    const int wid  = tid >> 6;
    const int lane = tid & 63;

    // Gaussian weights (runtime expf to match reference), pinned to SGPR
    float g[11];
    {
        float s = 0.f;
#pragma unroll
        for (int i = 0; i < 11; ++i) {
            float d = (float)(i - 5);
            g[i] = expf(-d * d * (1.0f / 4.5f));
            s += g[i];
        }
        float inv = 1.0f / s;
#pragma unroll
        for (int i = 0; i < 11; ++i) {
            g[i] *= inv;
            g[i] = __uint_as_float(__builtin_amdgcn_readfirstlane(__float_as_uint(g[i])));
        }
    }

    const int oyb = blockIdx.x * TH;      // output rows owned: [oyb, oyb+TH)
    const int Y0  = min(oyb, H - NR);     // shift last tile up; rows in-bounds
    const int plane = blockIdx.y;         // b*3 + c
    const size_t pbase = (size_t)plane * (H * W);
    const float* __restrict__ p1 = img1 + pbase;
    const float* __restrict__ p2 = img2 + pbase;

    const int c0 = wid * WSPAN + 2 * lane;             // even main col (<=510)
    const int ch = min(wid * WSPAN + 128 + 2 * lane, W - 2);  // halo unit col
    const bool hl = (lane < 5);                        // 5 halo units (10 cols)
    const float mA = (c0     < OUT_W) ? 1.0f : 0.0f;   // col A valid
    const float mB = (c0 + 1 < OUT_W) ? 1.0f : 0.0f;   // col B valid

    float4* const st = stg[wid];

    // 11 phase slots x 5 quantities x 2 columns of vertical partial sums
    float a0A[11], a1A[11], a2A[11], a3A[11], a4A[11];
    float a0B[11], a1B[11], a2B[11], a3B[11], a4B[11];
#pragma unroll
    for (int i = 0; i < 11; ++i) {
        a0A[i]=0.f; a1A[i]=0.f; a2A[i]=0.f; a3A[i]=0.f; a4A[i]=0.f;
        a0B[i]=0.f; a1B[i]=0.f; a2B[i]=0.f; a3B[i]=0.f; a4B[i]=0.f;
    }

    float lsum = 0.f;

    // wave-uniform row offset (SALU add+min)
    int ro = Y0 * W;
    const int rocap = (H - 1) * W;

    // prime prefetch (row Y0): main 2-col float2 pair from each image
    float2 va = *(const float2*)(p1 + ro + c0);
    float2 vb = *(const float2*)(p2 + ro + c0);
    float2 ha = make_float2(0.f, 0.f), hb = make_float2(0.f, 0.f);
    if (hl) { ha = *(const float2*)(p1 + ro + ch); hb = *(const float2*)(p2 + ro + ch); }

#pragma unroll 1
    for (int rb = 0; rb < NR; rb += 11) {
#pragma unroll
        for (int p = 0; p < 11; ++p) {
            const int r = rb + p;

            // stage row r: unit l = (x1[c0], x2[c0], x1[c0+1], x2[c0+1])
            st[lane] = make_float4(va.x, vb.x, va.y, vb.y);
            if (hl) st[64 + lane] = make_float4(ha.x, hb.x, ha.y, hb.y);

            // prefetch row r+1 (drains at NEXT row's ds_write; no barrier drain)
            ro = min(ro + W, rocap);
            va = *(const float2*)(p1 + ro + c0);
            vb = *(const float2*)(p2 + ro + c0);
            if (hl) { ha = *(const float2*)(p1 + ro + ch); hb = *(const float2*)(p2 + ro + ch); }

            __builtin_amdgcn_wave_barrier();   // pin: writes above, reads below

            // horizontal conv, both columns; products once per element
            float hA0, hA1, hA2, hA3, hA4;
            float hB0, hB1, hB2, hB3, hB4;
            {
                const float4* rp = st + lane;
#pragma unroll
                for (int k = 0; k < 6; ++k) {
                    const float4 f = rp[k];        // units l+k: elems 2k, 2k+1
                    {   // element e = 2k: (x1,x2) = (f.x, f.y)
                        const int e = 2 * k;
                        const float x1 = f.x, x2 = f.y;
                        const float q11 = x1 * x1, q22 = x2 * x2, q12 = x1 * x2;
                        if (e == 0) {
                            const float w = g[0];
                            hA0 = w * x1; hA1 = w * x2; hA2 = w * q11;
                            hA3 = w * q22; hA4 = w * q12;
                        } else if (e <= 10) {
                            const float w = g[e];
                            hA0 = fmaf(w, x1,  hA0); hA1 = fmaf(w, x2,  hA1);
                            hA2 = fmaf(w, q11, hA2); hA3 = fmaf(w, q22, hA3);
                            hA4 = fmaf(w, q12, hA4);
                        }
                        if (e >= 1) {                // B weight g[e-1]
                            const float w = g[e - 1];
                            hB0 = fmaf(w, x1,  hB0); hB1 = fmaf(w, x2,  hB1);
                            hB2 = fmaf(w, q11, hB2); hB3 = fmaf(w, q22, hB3);
                            hB4 = fmaf(w, q12, hB4);
                        }
                    }
                    {   // element e = 2k+1: (x1,x2) = (f.z, f.w)
                        const int e = 2 * k + 1;
                        const float x1 = f.z, x2 = f.w;
                        const float q11 = x1 * x1, q22 = x2 * x2, q12 = x1 * x2;
                        if (e <= 10) {
                            const float w = g[e];
                            hA0 = fmaf(w, x1,  hA0); hA1 = fmaf(w, x2,  hA1);
                            hA2 = fmaf(w, q11, hA2); hA3 = fmaf(w, q22, hA3);
                            hA4 = fmaf(w, q12, hA4);
                        }
                        if (e == 1) {                // first B write (mul)
                            const float w = g[0];
                            hB0 = w * x1; hB1 = w * x2; hB2 = w * q11;
                            hB3 = w * q22; hB4 = w * q12;
                        } else {                     // e-1 in 1..10
                            const float w = g[e - 1];
                            hB0 = fmaf(w, x1,  hB0); hB1 = fmaf(w, x2,  hB1);
                            hB2 = fmaf(w, q11, hB2); hB3 = fmaf(w, q22, hB3);
                            hB4 = fmaf(w, q12, hB4);
                        }
                    }
                }
            }

            __builtin_amdgcn_wave_barrier();   // pin: reads above next row's writes

            // vertical scatter, both columns: slot a==p gets mul (first write
            // after its flush at end of phase p-1)
#pragma unroll
            for (int a = 0; a < 11; ++a) {
                const float w = g[(p - a + 11) % 11];   // compile-time -> SGPR
                if (a == p) {
                    a0A[a] = w * hA0; a1A[a] = w * hA1; a2A[a] = w * hA2;
                    a3A[a] = w * hA3; a4A[a] = w * hA4;
                    a0B[a] = w * hB0; a1B[a] = w * hB1; a2B[a] = w * hB2;
                    a3B[a] = w * hB3; a4B[a] = w * hB4;
                } else {
                    a0A[a] = fmaf(w, hA0, a0A[a]); a1A[a] = fmaf(w, hA1, a1A[a]);
                    a2A[a] = fmaf(w, hA2, a2A[a]); a3A[a] = fmaf(w, hA3, a3A[a]);
                    a4A[a] = fmaf(w, hA4, a4A[a]);
                    a0B[a] = fmaf(w, hB0, a0B[a]); a1B[a] = fmaf(w, hB1, a1B[a]);
                    a2B[a] = fmaf(w, hB2, a2B[a]); a3B[a] = fmaf(w, hB3, a3B[a]);
                    a4B[a] = fmaf(w, hB4, a4B[a]);
                }
            }

            // output row oy = Y0 + r - 10 completes in slot e = (p+1)%11
            if (r >= 10) {
                const int e = (p + 1) % 11;
                const int oy = Y0 + r - 10;            // uniform (SALU)
                if (oy >= oyb) {                       // ownership (de-dup last tile)
                    {   // column A (c0)
                        const float m1 = a0A[e], m2 = a1A[e];
                        const float m1s = m1 * m1, m2s = m2 * m2, m12 = m1 * m2;
                        const float sig1  = a2A[e] - m1s;
                        const float sig2  = a3A[e] - m2s;
                        const float sig12 = a4A[e] - m12;
                        const float num = (2.f * m12 + C1c) * (2.f * sig12 + C2c);
                        const float den = (m1s + m2s + C1c) * (sig1 + sig2 + C2c);
                        lsum = fmaf(mA, num * __builtin_amdgcn_rcpf(den), lsum);
                    }
                    {   // column B (c0+1)
                        const float m1 = a0B[e], m2 = a1B[e];
                        const float m1s = m1 * m1, m2s = m2 * m2, m12 = m1 * m2;
                        const float sig1  = a2B[e] - m1s;
                        const float sig2  = a3B[e] - m2s;
                        const float sig12 = a4B[e] - m12;
                        const float num = (2.f * m12 + C1c) * (2.f * sig12 + C2c);
                        const float den = (m1s + m2s + C1c) * (sig1 + sig2 + C2c);
                        lsum = fmaf(mB, num * __builtin_amdgcn_rcpf(den), lsum);
                    }
                }
            }
        }
    }

    // per-wave reduce, then one cross-wave combine + one atomic per block
#pragma unroll
    for (int off = 32; off > 0; off >>= 1) lsum += __shfl_down(lsum, off, 64);
    if (lane == 0) wsum[wid] = lsum;
    __syncthreads();
    if (tid == 0) {
        const float inv_count = 1.0f / (3.0f * (float)OUT_H * (float)OUT_W);
        const float total = (wsum[0] + wsum[1] + wsum[2] + wsum[3]) * inv_count;
        atomicAdd(&out[plane / 3], total);
    }
}

__global__ void zero_out(float* out, int n) {
    int i = threadIdx.x + blockIdx.x * blockDim.x;
    if (i < n) out[i] = 0.f;
}

extern "C" void kernel_launch(void* const* d_in, const int* in_sizes, int n_in,
                              void* d_out, int out_size, void* d_ws, size_t ws_size,
                              hipStream_t stream) {
    const float* img1 = (const float*)d_in[0];
    const float* img2 = (const float*)d_in[1];
    float* out = (float*)d_out;

    zero_out<<<1, 64, 0, stream>>>(out, out_size);

    const int nplanes = in_sizes[0] / (H * W);          // 96
    dim3 grid((OUT_H + TH - 1) / TH,                    // 9 row-tiles
              nplanes);                                 // 96 planes -> 864 blocks
    ssim_kernel<<<grid, 256, 0, stream>>>(img1, img2, out);
}